// Round 9
// baseline (18213.405 us; speedup 1.0000x reference)
//
#include <hip/hip_runtime.h>
#include <math.h>

#define T_STEPS 2048
#define BATCH   64
#define HDIM    512
#define GDIM    2048   // 4*H
#define INDIM   256
#define NBLK_RE 128    // recurrence workgroups PER LAYER (1 per 4 h-dims)
#define HB_STEP (HDIM * BATCH)   // elements per timestep slot

typedef _Float16 f16x8 __attribute__((ext_vector_type(8)));
typedef _Float16 f16x4 __attribute__((ext_vector_type(4)));
typedef float    f32x4 __attribute__((ext_vector_type(4)));

__device__ __forceinline__ float sigf(float x) { return 1.0f / (1.0f + __expf(-x)); }
__device__ __forceinline__ float tanh_fast(float x) {
    return 1.0f - 2.0f / (__expf(2.0f * x) + 1.0f);   // saturates correctly
}

// ---------------------------------------------------------------------------
// fp32 -> fp16 conversion (weights once per launch; x once, 67 MB)
// ---------------------------------------------------------------------------
__global__ __launch_bounds__(256) void cvt_f16(const float* __restrict__ src,
                                               _Float16* __restrict__ dst, int n4)
{
    int i = blockIdx.x * 256 + threadIdx.x;
    if (i < n4) {
        float4 v = ((const float4*)src)[i];
        f16x4 h;
        h[0] = (_Float16)v.x; h[1] = (_Float16)v.y;
        h[2] = (_Float16)v.z; h[3] = (_Float16)v.w;
        ((f16x4*)dst)[i] = h;
    }
}

// ---------------------------------------------------------------------------
// MFMA xg-GEMM: xg[t][n][b] = sum_k x[t][b][k]*W_ih1[n][k] + bih1[n]+bhh1[n],
// fp16 out. Replaces both the old 20-TF fp32 VALU GEMM (R0: 7-14 ms) and the
// in-recurrence x-fold (R2-R8: the 8 HBM loads + 8 MFMAs at the loop top
// whose latency jitter inflated the 128-WG barrier every step).
// Same fragment math as the recurrence kernel (verified R1-R8): A rows =
// batches (lane&15), B cols = gate rows (grow), D col=l16 -> n, row=quad*4+r
// -> batch. Grid (128 WGs x 8 t-slices); W-frags pinned; no sync.
// ---------------------------------------------------------------------------
__global__ __launch_bounds__(256) void gemm_xg_mfma(
    const _Float16* __restrict__ xh,     // [nsteps][64][256] chunk base
    const _Float16* __restrict__ Wfi,    // W_ih1 [2048][256] fp16
    const float* __restrict__ b1, const float* __restrict__ b2,
    _Float16* __restrict__ xg, int nsteps)
{
    const int wg   = blockIdx.x;         // 0..127 -> 16 gate rows
    const int j0   = wg * 4;
    const int tid  = threadIdx.x;
    const int wv   = tid >> 6;           // wave = 16 batches
    const int ln   = tid & 63;
    const int l16  = ln & 15;
    const int quad = ln >> 4;
    const int grow = (l16 >> 2) * HDIM + j0 + (l16 & 3);

    f16x8 Bx[8];
#pragma unroll
    for (int j = 0; j < 8; j++) {
        const uint4 u = *(const uint4*)&Wfi[(size_t)grow * INDIM + j * 32 + quad * 8];
        Bx[j] = __builtin_bit_cast(f16x8, u);
    }
    const float bias = b1[grow] + b2[grow];

    const int ts = nsteps >> 3;          // nsteps divisible by 8 for all cands
    const int t0 = blockIdx.y * ts;
    for (int t = t0; t < t0 + ts; t++) {
        const _Float16* xp = xh + ((size_t)t * BATCH + 16 * wv + l16) * INDIM
                           + quad * 8;
        ulonglong2 a[8];
#pragma unroll
        for (int j = 0; j < 8; j++)
            a[j] = *(const ulonglong2*)(xp + j * 32);
        f32x4 acc0 = {0.f, 0.f, 0.f, 0.f}, acc1 = {0.f, 0.f, 0.f, 0.f};
#pragma unroll
        for (int j = 0; j < 8; j += 2) {
            acc0 = __builtin_amdgcn_mfma_f32_16x16x32_f16(
                __builtin_bit_cast(f16x8, a[j]),     Bx[j],     acc0, 0, 0, 0);
            acc1 = __builtin_amdgcn_mfma_f32_16x16x32_f16(
                __builtin_bit_cast(f16x8, a[j + 1]), Bx[j + 1], acc1, 0, 0, 0);
        }
        f32x4 d = acc0 + acc1;
        f16x4 o;
#pragma unroll
        for (int r = 0; r < 4; r++) o[r] = (_Float16)(d[r] + bias);
        *(uint2*)&xg[((size_t)t * GDIM + grow) * BATCH + 16 * wv + quad * 4]
            = __builtin_bit_cast(uint2, o);
    }
}

// ---------------------------------------------------------------------------
// Fused 2-layer MFMA LSTM — VERBATIM R1 structure (measured 4.4 us/step),
// xg now fp16. 256 WGs: 0..127 layer 1, 128..255 layer 2 (W_ih2@h1 folded).
// Layer 1 prefetches 4 scalar xg values BEFORE the wait (tiny, no MFMA work
// on the pre-wait path). Barrier: single counter per layer, wave0-tid0
// vmcnt-drain + fetch_add; all threads spin one relaxed agent load.
// h buffers batch-major [t][b][512]; packed 8B publish via hsm + wave 0.
// ---------------------------------------------------------------------------
__global__ __launch_bounds__(256, 1) void lstm_fused(
    const _Float16* __restrict__ xg,     // [nsteps][2048][64] fp16 (chunk base)
    const _Float16* __restrict__ Wf1,    // W_hh1 [2048][512]
    const _Float16* __restrict__ Wf2i,   // W_ih2 [2048][512]
    const _Float16* __restrict__ Wf2h,   // W_hh2 [2048][512]
    const float* __restrict__ bih2,      // [2048]
    const float* __restrict__ bhh2,      // [2048]
    _Float16* __restrict__ hb1,          // [nsteps+1][64][512]
    _Float16* __restrict__ hb2,
    float* __restrict__ c1,              // [512][64]
    float* __restrict__ c2,
    unsigned* __restrict__ ctr1,
    unsigned* __restrict__ ctr2,
    int nsteps)
{
    __shared__ float    gl[16][68];      // gate exchange, padded
    __shared__ _Float16 hsm[64][4];      // packed h per batch

    const int tid   = threadIdx.x;
    const int layer = blockIdx.x >> 7;
    const int wg    = blockIdx.x & (NBLK_RE - 1);
    const int j0    = wg * 4;
    const int wv    = tid >> 6;          // wave = M-tile
    const int ln    = tid & 63;
    const int l16   = ln & 15;
    const int quad  = ln >> 4;
    const int grow  = (l16 >> 2) * HDIM + j0 + (l16 & 3);
    const int du    = wv;                // update thread: dim j0+du, batch bu
    const int bu    = tid & 63;

    if (layer == 0) {
        // ------------------------- layer 1 -------------------------
        f16x8 Bf[16];
#pragma unroll
        for (int j = 0; j < 16; j++) {
            const uint4 u = *(const uint4*)&Wf1[(size_t)grow * HDIM + j * 32 + quad * 8];
            Bf[j] = __builtin_bit_cast(f16x8, u);
        }
        float c_reg = c1[(size_t)(j0 + du) * BATCH + bu];

        const size_t xo0 = (size_t)(0 * HDIM + j0 + du) * BATCH + bu;
        const size_t xo1 = (size_t)(1 * HDIM + j0 + du) * BATCH + bu;
        const size_t xo2 = (size_t)(2 * HDIM + j0 + du) * BATCH + bu;
        const size_t xo3 = (size_t)(3 * HDIM + j0 + du) * BATCH + bu;

        for (int t = 0; t < nsteps; t++) {
            // prefetch xg (4 scalar fp16 loads; independent of barrier)
            const _Float16* xgt = xg + (size_t)t * GDIM * BATCH;
            float x0 = (float)xgt[xo0], x1 = (float)xgt[xo1];
            float x2 = (float)xgt[xo2], x3 = (float)xgt[xo3];

            if (t > 0) {
                const unsigned tgt = (unsigned)(NBLK_RE * t);
                while (__hip_atomic_load(ctr1, __ATOMIC_RELAXED,
                                         __HIP_MEMORY_SCOPE_AGENT) < tgt) {}
                __atomic_signal_fence(__ATOMIC_ACQUIRE);
            }

            const _Float16* hp = hb1 + (size_t)t * HB_STEP
                               + (size_t)(16 * wv + l16) * HDIM + quad * 8;
            ulonglong2 a[16];
#pragma unroll
            for (int j = 0; j < 16; j++)
                a[j] = *(const ulonglong2*)(hp + j * 32);

            f32x4 acc0 = {0.f, 0.f, 0.f, 0.f}, acc1 = {0.f, 0.f, 0.f, 0.f};
#pragma unroll
            for (int j = 0; j < 16; j += 2) {
                acc0 = __builtin_amdgcn_mfma_f32_16x16x32_f16(
                    __builtin_bit_cast(f16x8, a[j]),     Bf[j],     acc0, 0, 0, 0);
                acc1 = __builtin_amdgcn_mfma_f32_16x16x32_f16(
                    __builtin_bit_cast(f16x8, a[j + 1]), Bf[j + 1], acc1, 0, 0, 0);
            }
            f32x4 d = acc0 + acc1;
            *(f32x4*)&gl[l16][16 * wv + quad * 4] = d;
            __syncthreads();

            {
                float si = gl[4 * 0 + du][bu] + x0;
                float sf = gl[4 * 1 + du][bu] + x1;
                float sg = gl[4 * 2 + du][bu] + x2;
                float so = gl[4 * 3 + du][bu] + x3;
                c_reg = sigf(sf) * c_reg + sigf(si) * tanh_fast(sg);
                float h = sigf(so) * tanh_fast(c_reg);
                hsm[bu][du] = (_Float16)h;
            }
            __syncthreads();   // hsm ready; also protects gl before next D-write

            if (tid < 64) {
                unsigned long long pk = *(const unsigned long long*)&hsm[tid][0];
                unsigned long long* dst = (unsigned long long*)
                    (hb1 + (size_t)(t + 1) * HB_STEP + (size_t)tid * HDIM + j0);
                __hip_atomic_store(dst, pk, __ATOMIC_RELAXED, __HIP_MEMORY_SCOPE_AGENT);
                if (t == nsteps - 1) {   // carry slot for next chunk
                    unsigned long long* dst0 = (unsigned long long*)
                        (hb1 + (size_t)tid * HDIM + j0);
                    __hip_atomic_store(dst0, pk, __ATOMIC_RELAXED, __HIP_MEMORY_SCOPE_AGENT);
                }
                if (tid == 0) {
                    asm volatile("s_waitcnt vmcnt(0)" ::: "memory");  // h at LLC
                    __hip_atomic_fetch_add(ctr1, 1u, __ATOMIC_RELAXED,
                                           __HIP_MEMORY_SCOPE_AGENT);
                }
            }
        }
        c1[(size_t)(j0 + du) * BATCH + bu] = c_reg;
    } else {
        // ------------------------- layer 2 -------------------------
        f16x8 Bh[16], Bi[16];
#pragma unroll
        for (int j = 0; j < 16; j++) {
            const uint4 uh = *(const uint4*)&Wf2h[(size_t)grow * HDIM + j * 32 + quad * 8];
            Bh[j] = __builtin_bit_cast(f16x8, uh);
            const uint4 ui = *(const uint4*)&Wf2i[(size_t)grow * HDIM + j * 32 + quad * 8];
            Bi[j] = __builtin_bit_cast(f16x8, ui);
        }
        float c_reg = c2[(size_t)(j0 + du) * BATCH + bu];
        const int dd = j0 + du;
        const float bi_ = bih2[0 * HDIM + dd] + bhh2[0 * HDIM + dd];
        const float bf_ = bih2[1 * HDIM + dd] + bhh2[1 * HDIM + dd];
        const float bg_ = bih2[2 * HDIM + dd] + bhh2[2 * HDIM + dd];
        const float bo_ = bih2[3 * HDIM + dd] + bhh2[3 * HDIM + dd];

        for (int t = 0; t < nsteps; t++) {
            f32x4 acc0 = {0.f, 0.f, 0.f, 0.f}, acc1 = {0.f, 0.f, 0.f, 0.f};

            // --- off-critical-path part first: W_ih2 @ h1[t+1] ---
            {
                const unsigned tgt = (unsigned)(NBLK_RE * (t + 1));
                while (__hip_atomic_load(ctr1, __ATOMIC_RELAXED,
                                         __HIP_MEMORY_SCOPE_AGENT) < tgt) {}
                __atomic_signal_fence(__ATOMIC_ACQUIRE);
            }
            {
                const _Float16* hp = hb1 + (size_t)(t + 1) * HB_STEP
                                   + (size_t)(16 * wv + l16) * HDIM + quad * 8;
                ulonglong2 a[16];
#pragma unroll
                for (int j = 0; j < 16; j++)
                    a[j] = *(const ulonglong2*)(hp + j * 32);
#pragma unroll
                for (int j = 0; j < 16; j += 2) {
                    acc0 = __builtin_amdgcn_mfma_f32_16x16x32_f16(
                        __builtin_bit_cast(f16x8, a[j]),     Bi[j],     acc0, 0, 0, 0);
                    acc1 = __builtin_amdgcn_mfma_f32_16x16x32_f16(
                        __builtin_bit_cast(f16x8, a[j + 1]), Bi[j + 1], acc1, 0, 0, 0);
                }
            }

            // --- critical path: own recurrence W_hh2 @ h2[t] ---
            if (t > 0) {
                const unsigned tgt = (unsigned)(NBLK_RE * t);
                while (__hip_atomic_load(ctr2, __ATOMIC_RELAXED,
                                         __HIP_MEMORY_SCOPE_AGENT) < tgt) {}
                __atomic_signal_fence(__ATOMIC_ACQUIRE);
            }
            {
                const _Float16* hp = hb2 + (size_t)t * HB_STEP
                                   + (size_t)(16 * wv + l16) * HDIM + quad * 8;
                ulonglong2 a[16];
#pragma unroll
                for (int j = 0; j < 16; j++)
                    a[j] = *(const ulonglong2*)(hp + j * 32);
#pragma unroll
                for (int j = 0; j < 16; j += 2) {
                    acc0 = __builtin_amdgcn_mfma_f32_16x16x32_f16(
                        __builtin_bit_cast(f16x8, a[j]),     Bh[j],     acc0, 0, 0, 0);
                    acc1 = __builtin_amdgcn_mfma_f32_16x16x32_f16(
                        __builtin_bit_cast(f16x8, a[j + 1]), Bh[j + 1], acc1, 0, 0, 0);
                }
            }
            f32x4 d = acc0 + acc1;
            *(f32x4*)&gl[l16][16 * wv + quad * 4] = d;
            __syncthreads();

            {
                float si = gl[4 * 0 + du][bu] + bi_;
                float sf = gl[4 * 1 + du][bu] + bf_;
                float sg = gl[4 * 2 + du][bu] + bg_;
                float so = gl[4 * 3 + du][bu] + bo_;
                c_reg = sigf(sf) * c_reg + sigf(si) * tanh_fast(sg);
                float h = sigf(so) * tanh_fast(c_reg);
                hsm[bu][du] = (_Float16)h;
            }
            __syncthreads();

            if (tid < 64) {
                unsigned long long pk = *(const unsigned long long*)&hsm[tid][0];
                unsigned long long* dst = (unsigned long long*)
                    (hb2 + (size_t)(t + 1) * HB_STEP + (size_t)tid * HDIM + j0);
                __hip_atomic_store(dst, pk, __ATOMIC_RELAXED, __HIP_MEMORY_SCOPE_AGENT);
                if (t == nsteps - 1) {
                    unsigned long long* dst0 = (unsigned long long*)
                        (hb2 + (size_t)tid * HDIM + j0);
                    __hip_atomic_store(dst0, pk, __ATOMIC_RELAXED, __HIP_MEMORY_SCOPE_AGENT);
                }
                if (tid == 0) {
                    asm volatile("s_waitcnt vmcnt(0)" ::: "memory");
                    __hip_atomic_fetch_add(ctr2, 1u, __ATOMIC_RELAXED,
                                           __HIP_MEMORY_SCOPE_AGENT);
                }
            }
        }
        c2[(size_t)(j0 + du) * BATCH + bu] = c_reg;
    }
}

// ---------------------------------------------------------------------------
// out[t*64+b] = sigmoid(dot(Wout, h2[t][b][:]) + bout); h2 fp16 [t][b][512]
// ---------------------------------------------------------------------------
__global__ __launch_bounds__(256) void out_kernel(
    const _Float16* __restrict__ h2, const float* __restrict__ Wout,
    const float* __restrict__ bout, float* __restrict__ out)
{
    const int t = blockIdx.x;
    const int q = threadIdx.x >> 6, b = threadIdx.x & 63;
    const _Float16* base = &h2[(size_t)t * HB_STEP + (size_t)b * HDIM];
    float s = 0.0f;
#pragma unroll 8
    for (int k = q * 128; k < q * 128 + 128; k += 4) {
        const uint2 u = *(const uint2*)&base[k];
        f16x4 h = __builtin_bit_cast(f16x4, u);
        s += Wout[k] * (float)h[0] + Wout[k + 1] * (float)h[1]
           + Wout[k + 2] * (float)h[2] + Wout[k + 3] * (float)h[3];
    }
    __shared__ float red[4][64];
    red[q][b] = s;
    __syncthreads();
    if (q == 0) {
        float v = red[0][b] + red[1][b] + red[2][b] + red[3][b] + bout[0];
        out[t * BATCH + b] = sigf(v);
    }
}

// ---------------------------------------------------------------------------
static size_t req_bytes(int C) {
    return 4096                                       // counters
         + 2ull * HDIM * BATCH * 4                    // c1, c2
         + 3ull * GDIM * HDIM * 2                     // Wf1h, Wf2i, Wf2h
         + (size_t)GDIM * INDIM * 2                   // Wf1i
         + (size_t)T_STEPS * BATCH * INDIM * 2        // xh (full sequence)
         + 2ull * (size_t)(C + 1) * BATCH * HDIM * 2  // hb1, hb2
         + (size_t)C * GDIM * BATCH * 2;              // xg fp16
}

extern "C" void kernel_launch(void* const* d_in, const int* in_sizes, int n_in,
                              void* d_out, int out_size, void* d_ws, size_t ws_size,
                              hipStream_t stream)
{
    const float* x    = (const float*)d_in[0];
    const float* Wih1 = (const float*)d_in[1];
    const float* Whh1 = (const float*)d_in[2];
    const float* bih1 = (const float*)d_in[3];
    const float* bhh1 = (const float*)d_in[4];
    const float* Wih2 = (const float*)d_in[5];
    const float* Whh2 = (const float*)d_in[6];
    const float* bih2 = (const float*)d_in[7];
    const float* bhh2 = (const float*)d_in[8];
    const float* Wout = (const float*)d_in[9];
    const float* bout = (const float*)d_in[10];
    float* out = (float*)d_out;

    int C = 256;
    const int cands[] = {2048, 1024, 512, 256};
    for (int i = 0; i < 4; i++)
        if (req_bytes(cands[i]) <= ws_size) { C = cands[i]; break; }

    char* p = (char*)d_ws;
    unsigned*  ctr   = (unsigned*)p;                p += 4096;
    float*     c1    = (float*)p;                   p += (size_t)HDIM * BATCH * 4;
    float*     c2    = (float*)p;                   p += (size_t)HDIM * BATCH * 4;
    _Float16*  Wf1h  = (_Float16*)p;                p += (size_t)GDIM * HDIM * 2;
    _Float16*  Wf1i  = (_Float16*)p;                p += (size_t)GDIM * INDIM * 2;
    _Float16*  Wf2i  = (_Float16*)p;                p += (size_t)GDIM * HDIM * 2;
    _Float16*  Wf2h  = (_Float16*)p;                p += (size_t)GDIM * HDIM * 2;
    _Float16*  xh    = (_Float16*)p;                p += (size_t)T_STEPS * BATCH * INDIM * 2;
    _Float16*  hb1   = (_Float16*)p;                p += (size_t)(C + 1) * BATCH * HDIM * 2;
    _Float16*  hb2   = (_Float16*)p;                p += (size_t)(C + 1) * BATCH * HDIM * 2;
    _Float16*  xg    = (_Float16*)p;

    // zero counters + c-state (contiguous) and the two h carry slots
    hipMemsetAsync(ctr, 0, 4096 + 2ull * HDIM * BATCH * 4, stream);
    hipMemsetAsync(hb1, 0, (size_t)BATCH * HDIM * 2, stream);
    hipMemsetAsync(hb2, 0, (size_t)BATCH * HDIM * 2, stream);

    // fp16 conversions
    cvt_f16<<<dim3(GDIM * HDIM / 4 / 256), dim3(256), 0, stream>>>(Whh1, Wf1h, GDIM * HDIM / 4);
    cvt_f16<<<dim3(GDIM * INDIM / 4 / 256), dim3(256), 0, stream>>>(Wih1, Wf1i, GDIM * INDIM / 4);
    cvt_f16<<<dim3(GDIM * HDIM / 4 / 256), dim3(256), 0, stream>>>(Wih2, Wf2i, GDIM * HDIM / 4);
    cvt_f16<<<dim3(GDIM * HDIM / 4 / 256), dim3(256), 0, stream>>>(Whh2, Wf2h, GDIM * HDIM / 4);
    cvt_f16<<<dim3(T_STEPS * BATCH * INDIM / 4 / 256), dim3(256), 0, stream>>>(
        x, xh, T_STEPS * BATCH * INDIM / 4);

    const _Float16* h2r = hb2 + (size_t)HB_STEP;   // slots 1..C
    int cidx = 0;

    for (int t0 = 0; t0 < T_STEPS; t0 += C, cidx++) {
        const _Float16* xc = xh + (size_t)t0 * BATCH * INDIM;
        gemm_xg_mfma<<<dim3(NBLK_RE, 8), dim3(256), 0, stream>>>(
            xc, Wf1i, bih1, bhh1, xg, C);

        unsigned* c1p = ctr + (size_t)cidx * 64;   // 256B-spaced per chunk
        unsigned* c2p = c1p + 32;                  // 128B from c1p
        void* args[] = {(void*)&xg, (void*)&Wf1h, (void*)&Wf2i, (void*)&Wf2h,
                        (void*)&bih2, (void*)&bhh2, (void*)&hb1, (void*)&hb2,
                        (void*)&c1, (void*)&c2, (void*)&c1p, (void*)&c2p, (void*)&C};
        hipLaunchCooperativeKernel((void*)lstm_fused, dim3(2 * NBLK_RE), dim3(256),
                                   args, 0, stream);

        out_kernel<<<dim3(C), dim3(256), 0, stream>>>(h2r, Wout, bout,
                                                      out + (size_t)t0 * BATCH);
    }

    (void)in_sizes; (void)n_in; (void)out_size;
}

// Round 11
// 11375.292 us; speedup vs baseline: 1.6011x; 1.6011x over previous
//
#include <hip/hip_runtime.h>
#include <math.h>

#define T_STEPS 2048
#define BATCH   64
#define HDIM    512
#define GDIM    2048   // 4*H
#define INDIM   256
#define NBLK_RE 128    // recurrence workgroups PER LAYER
#define HB_STEP (HDIM * BATCH)   // elements per timestep slot
#define GROUPS  4      // independent batch groups
#define WPG     32     // dim-WGs per group per layer
#define BPG     16     // batches per group

typedef _Float16 f16x8 __attribute__((ext_vector_type(8)));
typedef _Float16 f16x4 __attribute__((ext_vector_type(4)));
typedef float    f32x4 __attribute__((ext_vector_type(4)));

__device__ __forceinline__ float sigf(float x) { return 1.0f / (1.0f + __expf(-x)); }
__device__ __forceinline__ float tanh_fast(float x) {
    return 1.0f - 2.0f / (__expf(2.0f * x) + 1.0f);   // saturates correctly
}

// ---------------------------------------------------------------------------
// fp32 -> fp16 conversion (weights once per launch; x once, 67 MB)
// ---------------------------------------------------------------------------
__global__ __launch_bounds__(256) void cvt_f16(const float* __restrict__ src,
                                               _Float16* __restrict__ dst, int n4)
{
    int i = blockIdx.x * 256 + threadIdx.x;
    if (i < n4) {
        float4 v = ((const float4*)src)[i];
        f16x4 h;
        h[0] = (_Float16)v.x; h[1] = (_Float16)v.y;
        h[2] = (_Float16)v.z; h[3] = (_Float16)v.w;
        ((f16x4*)dst)[i] = h;
    }
}

// ---------------------------------------------------------------------------
// Group-scoped wave poll (R5-proven mechanism, domain 128 -> 32 flags).
// Lanes 0..31 each poll ONE 64B-strided flag of this group; __all combines.
// No __syncthreads in the loop. Flags hold absolute step numbers.
// ---------------------------------------------------------------------------
__device__ __forceinline__ void wait_flags_grp(const unsigned* __restrict__ flags,
                                               int g, unsigned tgt, int ln)
{
    const unsigned* p = flags + (size_t)(g * WPG + (ln & 31)) * 16;
    for (;;) {
        unsigned f = (ln < 32)
            ? __hip_atomic_load(p, __ATOMIC_RELAXED, __HIP_MEMORY_SCOPE_AGENT)
            : tgt;
        if (__all((int)(f >= tgt))) break;
    }
    __atomic_signal_fence(__ATOMIC_ACQUIRE);
}

// ---------------------------------------------------------------------------
// Fully-fused 2-layer MFMA LSTM, BATCH-GROUPED. 256 WGs: bit7 = layer;
// within a layer, wgl = g*32 + w: group g (batches 16g..16g+15), dim-WG w
// (h-dims j0=16w..+15). Batches are independent in the recurrence, so the
// 4 groups are fully decoupled pipelines: sync domain = 32 producers (was
// 128), per-WG h gather = 16 KB/step (was 64 KB). Per wave: dims j0+4wv..+3
// x 4 gates = 16 gate rows x 16 batches, K=512 -> 16 MFMAs (same count as
// R5). VERIFIED PRIMITIVES UNCHANGED: batch-major h [t][b][512], 16B
// fragment loads, hsm-staged 8B publish + vmcnt drain + flag, R5 poll.
// ---------------------------------------------------------------------------
__global__ __launch_bounds__(256, 1) void lstm_fused(
    const _Float16* __restrict__ xh,     // [nsteps][64][256] fp16 (batch-major)
    const _Float16* __restrict__ Wf1h,   // W_hh1 [2048][512]
    const _Float16* __restrict__ Wf1i,   // W_ih1 [2048][256]
    const _Float16* __restrict__ Wf2i,   // W_ih2 [2048][512]
    const _Float16* __restrict__ Wf2h,   // W_hh2 [2048][512]
    const float* __restrict__ bih1, const float* __restrict__ bhh1,
    const float* __restrict__ bih2, const float* __restrict__ bhh2,
    _Float16* __restrict__ hb1,          // [nsteps+1][64][512] batch-major
    _Float16* __restrict__ hb2,
    float* __restrict__ c1,              // [512][64]
    float* __restrict__ c2,
    unsigned* __restrict__ flag1,        // [128] @ 64B stride (g*32+w)
    unsigned* __restrict__ flag2,
    int nsteps, unsigned t0a)
{
    __shared__ float    gl[4][16][20];   // [gate][dim16][batch16], padded
    __shared__ _Float16 hsm[16][16];     // [batch16][dim16]

    const int tid   = threadIdx.x;
    const int layer = blockIdx.x >> 7;
    const int wgl   = blockIdx.x & (NBLK_RE - 1);
    const int g     = wgl >> 5;          // batch group 0..3
    const int w     = wgl & 31;          // dim-WG 0..31
    const int j0    = w * 16;            // dim base (16 dims per WG)
    const int wv    = tid >> 6;          // wave: dims j0+4wv..+3
    const int ln    = tid & 63;
    const int l16   = ln & 15;
    const int quad  = ln >> 4;
    const int grow  = (l16 >> 2) * HDIM + j0 + 4 * wv + (l16 & 3);
    const int d16   = tid >> 4;          // pointwise: dim within WG 0..15
    const int b16   = tid & 15;          // pointwise: batch within group
    const int dd    = j0 + d16;
    const int bu    = g * BPG + b16;
    const int arow  = g * BPG + l16;     // A-fragment batch row

    if (layer == 0) {
        // ------------------------- layer 1 -------------------------
        f16x8 Bh[16], Bx[8];
#pragma unroll
        for (int j = 0; j < 16; j++) {
            const uint4 u = *(const uint4*)&Wf1h[(size_t)grow * HDIM + j * 32 + quad * 8];
            Bh[j] = __builtin_bit_cast(f16x8, u);
        }
#pragma unroll
        for (int j = 0; j < 8; j++) {
            const uint4 u = *(const uint4*)&Wf1i[(size_t)grow * INDIM + j * 32 + quad * 8];
            Bx[j] = __builtin_bit_cast(f16x8, u);
        }
        float c_reg = c1[(size_t)dd * BATCH + bu];
        const float bi_ = bih1[0 * HDIM + dd] + bhh1[0 * HDIM + dd];
        const float bf_ = bih1[1 * HDIM + dd] + bhh1[1 * HDIM + dd];
        const float bg_ = bih1[2 * HDIM + dd] + bhh1[2 * HDIM + dd];
        const float bo_ = bih1[3 * HDIM + dd] + bhh1[3 * HDIM + dd];

        for (int t = 0; t < nsteps; t++) {
            f32x4 ax0 = {0.f, 0.f, 0.f, 0.f}, ax1 = {0.f, 0.f, 0.f, 0.f};

            // --- x contribution first (independent accumulators; no dep) ---
            {
                const _Float16* xp = xh + ((size_t)t * BATCH + arow) * INDIM
                                   + quad * 8;
                ulonglong2 ax[8];
#pragma unroll
                for (int j = 0; j < 8; j++)
                    ax[j] = *(const ulonglong2*)(xp + j * 32);
#pragma unroll
                for (int j = 0; j < 8; j += 2) {
                    ax0 = __builtin_amdgcn_mfma_f32_16x16x32_f16(
                        __builtin_bit_cast(f16x8, ax[j]),     Bx[j],     ax0, 0, 0, 0);
                    ax1 = __builtin_amdgcn_mfma_f32_16x16x32_f16(
                        __builtin_bit_cast(f16x8, ax[j + 1]), Bx[j + 1], ax1, 0, 0, 0);
                }
            }

            // --- critical path: W_hh1 @ h1[t] (group batches only) ---
            wait_flags_grp(flag1, g, t0a + (unsigned)t, ln);
            f32x4 ah0 = {0.f, 0.f, 0.f, 0.f}, ah1 = {0.f, 0.f, 0.f, 0.f};
            f32x4 ah2 = {0.f, 0.f, 0.f, 0.f}, ah3 = {0.f, 0.f, 0.f, 0.f};
            {
                const _Float16* hp = hb1 + (size_t)t * HB_STEP
                                   + (size_t)arow * HDIM + quad * 8;
                ulonglong2 a[16];
#pragma unroll
                for (int j = 0; j < 16; j++)
                    a[j] = *(const ulonglong2*)(hp + j * 32);
#pragma unroll
                for (int j = 0; j < 16; j += 4) {
                    ah0 = __builtin_amdgcn_mfma_f32_16x16x32_f16(
                        __builtin_bit_cast(f16x8, a[j]),     Bh[j],     ah0, 0, 0, 0);
                    ah1 = __builtin_amdgcn_mfma_f32_16x16x32_f16(
                        __builtin_bit_cast(f16x8, a[j + 1]), Bh[j + 1], ah1, 0, 0, 0);
                    ah2 = __builtin_amdgcn_mfma_f32_16x16x32_f16(
                        __builtin_bit_cast(f16x8, a[j + 2]), Bh[j + 2], ah2, 0, 0, 0);
                    ah3 = __builtin_amdgcn_mfma_f32_16x16x32_f16(
                        __builtin_bit_cast(f16x8, a[j + 3]), Bh[j + 3], ah3, 0, 0, 0);
                }
            }
            f32x4 d = (ax0 + ax1) + ((ah0 + ah1) + (ah2 + ah3));
            // D: col=l16 -> gate row (gate=l16>>2, dim16=4wv+(l16&3));
            //    row=quad*4+r -> batch16
            *(f32x4*)&gl[l16 >> 2][4 * wv + (l16 & 3)][quad * 4] = d;
            __syncthreads();

            {
                float si = gl[0][d16][b16] + bi_;
                float sf = gl[1][d16][b16] + bf_;
                float sg = gl[2][d16][b16] + bg_;
                float so = gl[3][d16][b16] + bo_;
                c_reg = sigf(sf) * c_reg + sigf(si) * tanh_fast(sg);
                float h = sigf(so) * tanh_fast(c_reg);
                hsm[b16][d16] = (_Float16)h;
            }
            __syncthreads();   // hsm ready; also protects gl before next D-write

            // --- packed publish (wave 0): 16 batches x 8B quads ---
            if (tid < 64) {
                const int pb = tid >> 2, pd = tid & 3;     // batch16, dim-quad
                unsigned long long pk = *(const unsigned long long*)&hsm[pb][pd * 4];
                unsigned long long* dst = (unsigned long long*)
                    (hb1 + (size_t)(t + 1) * HB_STEP
                         + (size_t)(g * BPG + pb) * HDIM + j0 + pd * 4);
                __hip_atomic_store(dst, pk, __ATOMIC_RELAXED, __HIP_MEMORY_SCOPE_AGENT);
                if (t == nsteps - 1) {   // carry slot for next chunk
                    unsigned long long* dst0 = (unsigned long long*)
                        (hb1 + (size_t)(g * BPG + pb) * HDIM + j0 + pd * 4);
                    __hip_atomic_store(dst0, pk, __ATOMIC_RELAXED, __HIP_MEMORY_SCOPE_AGENT);
                }
                if (tid == 0) {
                    asm volatile("s_waitcnt vmcnt(0)" ::: "memory");  // h at LLC
                    __hip_atomic_store(flag1 + (size_t)wgl * 16, t0a + (unsigned)t + 1u,
                                       __ATOMIC_RELAXED, __HIP_MEMORY_SCOPE_AGENT);
                }
            }
        }
        c1[(size_t)dd * BATCH + bu] = c_reg;
    } else {
        // ------------------------- layer 2 -------------------------
        f16x8 Bh[16], Bi[16];
#pragma unroll
        for (int j = 0; j < 16; j++) {
            const uint4 uh = *(const uint4*)&Wf2h[(size_t)grow * HDIM + j * 32 + quad * 8];
            Bh[j] = __builtin_bit_cast(f16x8, uh);
            const uint4 ui = *(const uint4*)&Wf2i[(size_t)grow * HDIM + j * 32 + quad * 8];
            Bi[j] = __builtin_bit_cast(f16x8, ui);
        }
        float c_reg = c2[(size_t)dd * BATCH + bu];
        const float bi_ = bih2[0 * HDIM + dd] + bhh2[0 * HDIM + dd];
        const float bf_ = bih2[1 * HDIM + dd] + bhh2[1 * HDIM + dd];
        const float bg_ = bih2[2 * HDIM + dd] + bhh2[2 * HDIM + dd];
        const float bo_ = bih2[3 * HDIM + dd] + bhh2[3 * HDIM + dd];

        for (int t = 0; t < nsteps; t++) {
            f32x4 ai0 = {0.f, 0.f, 0.f, 0.f}, ai1 = {0.f, 0.f, 0.f, 0.f};
            f32x4 ag0 = {0.f, 0.f, 0.f, 0.f}, ag1 = {0.f, 0.f, 0.f, 0.f};

            // --- W_ih2 @ h1[t+1] (group g's h1 only) ---
            wait_flags_grp(flag1, g, t0a + (unsigned)t + 1u, ln);
            {
                const _Float16* hp = hb1 + (size_t)(t + 1) * HB_STEP
                                   + (size_t)arow * HDIM + quad * 8;
                ulonglong2 a[16];
#pragma unroll
                for (int j = 0; j < 16; j++)
                    a[j] = *(const ulonglong2*)(hp + j * 32);
#pragma unroll
                for (int j = 0; j < 16; j += 2) {
                    ai0 = __builtin_amdgcn_mfma_f32_16x16x32_f16(
                        __builtin_bit_cast(f16x8, a[j]),     Bi[j],     ai0, 0, 0, 0);
                    ai1 = __builtin_amdgcn_mfma_f32_16x16x32_f16(
                        __builtin_bit_cast(f16x8, a[j + 1]), Bi[j + 1], ai1, 0, 0, 0);
                }
            }

            // --- critical path: W_hh2 @ h2[t] ---
            wait_flags_grp(flag2, g, t0a + (unsigned)t, ln);
            {
                const _Float16* hp = hb2 + (size_t)t * HB_STEP
                                   + (size_t)arow * HDIM + quad * 8;
                ulonglong2 a[16];
#pragma unroll
                for (int j = 0; j < 16; j++)
                    a[j] = *(const ulonglong2*)(hp + j * 32);
#pragma unroll
                for (int j = 0; j < 16; j += 2) {
                    ag0 = __builtin_amdgcn_mfma_f32_16x16x32_f16(
                        __builtin_bit_cast(f16x8, a[j]),     Bh[j],     ag0, 0, 0, 0);
                    ag1 = __builtin_amdgcn_mfma_f32_16x16x32_f16(
                        __builtin_bit_cast(f16x8, a[j + 1]), Bh[j + 1], ag1, 0, 0, 0);
                }
            }
            f32x4 d = (ai0 + ai1) + (ag0 + ag1);
            *(f32x4*)&gl[l16 >> 2][4 * wv + (l16 & 3)][quad * 4] = d;
            __syncthreads();

            {
                float si = gl[0][d16][b16] + bi_;
                float sf = gl[1][d16][b16] + bf_;
                float sg = gl[2][d16][b16] + bg_;
                float so = gl[3][d16][b16] + bo_;
                c_reg = sigf(sf) * c_reg + sigf(si) * tanh_fast(sg);
                float h = sigf(so) * tanh_fast(c_reg);
                hsm[b16][d16] = (_Float16)h;
            }
            __syncthreads();

            if (tid < 64) {
                const int pb = tid >> 2, pd = tid & 3;
                unsigned long long pk = *(const unsigned long long*)&hsm[pb][pd * 4];
                unsigned long long* dst = (unsigned long long*)
                    (hb2 + (size_t)(t + 1) * HB_STEP
                         + (size_t)(g * BPG + pb) * HDIM + j0 + pd * 4);
                __hip_atomic_store(dst, pk, __ATOMIC_RELAXED, __HIP_MEMORY_SCOPE_AGENT);
                if (t == nsteps - 1) {
                    unsigned long long* dst0 = (unsigned long long*)
                        (hb2 + (size_t)(g * BPG + pb) * HDIM + j0 + pd * 4);
                    __hip_atomic_store(dst0, pk, __ATOMIC_RELAXED, __HIP_MEMORY_SCOPE_AGENT);
                }
                if (tid == 0) {
                    asm volatile("s_waitcnt vmcnt(0)" ::: "memory");
                    __hip_atomic_store(flag2 + (size_t)wgl * 16, t0a + (unsigned)t + 1u,
                                       __ATOMIC_RELAXED, __HIP_MEMORY_SCOPE_AGENT);
                }
            }
        }
        c2[(size_t)dd * BATCH + bu] = c_reg;
    }
}

// ---------------------------------------------------------------------------
// out[t*64+b] = sigmoid(dot(Wout, h2[t][b][:]) + bout); h2 fp16 [t][b][512]
// (unchanged from R5 — batch-major layout preserved)
// ---------------------------------------------------------------------------
__global__ __launch_bounds__(256) void out_kernel(
    const _Float16* __restrict__ h2, const float* __restrict__ Wout,
    const float* __restrict__ bout, float* __restrict__ out)
{
    const int t = blockIdx.x;
    const int q = threadIdx.x >> 6, b = threadIdx.x & 63;
    const _Float16* base = &h2[(size_t)t * HB_STEP + (size_t)b * HDIM];
    float s = 0.0f;
#pragma unroll 8
    for (int k = q * 128; k < q * 128 + 128; k += 4) {
        const uint2 u = *(const uint2*)&base[k];
        f16x4 h = __builtin_bit_cast(f16x4, u);
        s += Wout[k] * (float)h[0] + Wout[k + 1] * (float)h[1]
           + Wout[k + 2] * (float)h[2] + Wout[k + 3] * (float)h[3];
    }
    __shared__ float red[4][64];
    red[q][b] = s;
    __syncthreads();
    if (q == 0) {
        float v = red[0][b] + red[1][b] + red[2][b] + red[3][b] + bout[0];
        out[t * BATCH + b] = sigf(v);
    }
}

// ---------------------------------------------------------------------------
static size_t req_bytes(int C) {
    return 65536                                      // flag arrays
         + 2ull * HDIM * BATCH * 4                    // c1, c2
         + 3ull * GDIM * HDIM * 2                     // Wf1h, Wf2i, Wf2h
         + (size_t)GDIM * INDIM * 2                   // Wf1i
         + (size_t)T_STEPS * BATCH * INDIM * 2        // xh (full sequence)
         + 2ull * (size_t)(C + 1) * BATCH * HDIM * 2; // hb1, hb2
}

extern "C" void kernel_launch(void* const* d_in, const int* in_sizes, int n_in,
                              void* d_out, int out_size, void* d_ws, size_t ws_size,
                              hipStream_t stream)
{
    const float* x    = (const float*)d_in[0];
    const float* Wih1 = (const float*)d_in[1];
    const float* Whh1 = (const float*)d_in[2];
    const float* bih1 = (const float*)d_in[3];
    const float* bhh1 = (const float*)d_in[4];
    const float* Wih2 = (const float*)d_in[5];
    const float* Whh2 = (const float*)d_in[6];
    const float* bih2 = (const float*)d_in[7];
    const float* bhh2 = (const float*)d_in[8];
    const float* Wout = (const float*)d_in[9];
    const float* bout = (const float*)d_in[10];
    float* out = (float*)d_out;

    int C = 8;
    const int cands[] = {2048, 1024, 512, 256, 128, 64, 32, 16, 8};
    for (int i = 0; i < 9; i++)
        if (req_bytes(cands[i]) <= ws_size) { C = cands[i]; break; }

    char* p = (char*)d_ws;
    unsigned*  flag1 = (unsigned*)p;                p += 32768;
    unsigned*  flag2 = (unsigned*)p;                p += 32768;
    float*     c1    = (float*)p;                   p += (size_t)HDIM * BATCH * 4;
    float*     c2    = (float*)p;                   p += (size_t)HDIM * BATCH * 4;
    _Float16*  Wf1h  = (_Float16*)p;                p += (size_t)GDIM * HDIM * 2;
    _Float16*  Wf1i  = (_Float16*)p;                p += (size_t)GDIM * INDIM * 2;
    _Float16*  Wf2i  = (_Float16*)p;                p += (size_t)GDIM * HDIM * 2;
    _Float16*  Wf2h  = (_Float16*)p;                p += (size_t)GDIM * HDIM * 2;
    _Float16*  xh    = (_Float16*)p;                p += (size_t)T_STEPS * BATCH * INDIM * 2;
    _Float16*  hb1   = (_Float16*)p;                p += (size_t)(C + 1) * BATCH * HDIM * 2;
    _Float16*  hb2   = (_Float16*)p;

    // zero flags + c-state (contiguous) and the two h carry slots
    hipMemsetAsync(flag1, 0, 65536 + 2ull * HDIM * BATCH * 4, stream);
    hipMemsetAsync(hb1, 0, (size_t)BATCH * HDIM * 2, stream);
    hipMemsetAsync(hb2, 0, (size_t)BATCH * HDIM * 2, stream);

    // fp16 conversions
    cvt_f16<<<dim3(GDIM * HDIM / 4 / 256), dim3(256), 0, stream>>>(Whh1, Wf1h, GDIM * HDIM / 4);
    cvt_f16<<<dim3(GDIM * INDIM / 4 / 256), dim3(256), 0, stream>>>(Wih1, Wf1i, GDIM * INDIM / 4);
    cvt_f16<<<dim3(GDIM * HDIM / 4 / 256), dim3(256), 0, stream>>>(Wih2, Wf2i, GDIM * HDIM / 4);
    cvt_f16<<<dim3(GDIM * HDIM / 4 / 256), dim3(256), 0, stream>>>(Whh2, Wf2h, GDIM * HDIM / 4);
    cvt_f16<<<dim3(T_STEPS * BATCH * INDIM / 4 / 256), dim3(256), 0, stream>>>(
        x, xh, T_STEPS * BATCH * INDIM / 4);

    const _Float16* h2r = hb2 + (size_t)HB_STEP;   // slots 1..C

    for (int t0 = 0; t0 < T_STEPS; t0 += C) {
        const _Float16* xc = xh + (size_t)t0 * BATCH * INDIM;
        unsigned t0a = (unsigned)t0;
        void* args[] = {(void*)&xc, (void*)&Wf1h, (void*)&Wf1i, (void*)&Wf2i,
                        (void*)&Wf2h, (void*)&bih1, (void*)&bhh1, (void*)&bih2,
                        (void*)&bhh2, (void*)&hb1, (void*)&hb2, (void*)&c1,
                        (void*)&c2, (void*)&flag1, (void*)&flag2, (void*)&C,
                        (void*)&t0a};
        hipLaunchCooperativeKernel((void*)lstm_fused, dim3(2 * NBLK_RE), dim3(256),
                                   args, 0, stream);

        out_kernel<<<dim3(C), dim3(256), 0, stream>>>(h2r, Wout, bout,
                                                      out + (size_t)t0 * BATCH);
    }

    (void)in_sizes; (void)n_in; (void)out_size;
}